// Round 1
// baseline (33.737 us; speedup 1.0000x reference)
//
#include <hip/hip_runtime.h>

// ParallelMagLoss: per-row margin-substituted log-softmax CE + one_hot emit.
// Outputs (flat f32): [0]=loss.mean(), [1]=loss_g, [2..]=one_hot (B*C).

#define UA2_INV (1.0f / 12100.0f)   // 1 / (110^2)

__global__ __launch_bounds__(1024) void magloss_row_kernel(
    const float* __restrict__ ct,     // cos_theta      [B,C]
    const float* __restrict__ ctm,    // cos_theta_m    [B,C] (only target col used)
    const int*   __restrict__ target, // [B]
    float*       __restrict__ onehot, // d_out + 2      [B,C]
    float*       __restrict__ row_loss, // ws           [B]
    int C)
{
    const int row = blockIdx.x;
    const size_t base = (size_t)row * (size_t)C;
    const int t = target[row];
    const float ctm_t = ctm[base + (size_t)t];

    const int nchunk = C >> 2;          // float4 chunks
    const int t4 = t >> 2;

    const float4* __restrict__ ct4 = (const float4*)(ct + base);
    float2* __restrict__ oh2 = (float2*)(onehot + base);  // 8B-aligned only

    // branchless online softmax (per-thread partial)
    float m = -1e30f;
    float s = 0.0f;

    for (int c = threadIdx.x; c < nchunk; c += blockDim.x) {
        float4 v = ct4[c];
        float2 o0 = make_float2(0.f, 0.f);
        float2 o1 = make_float2(0.f, 0.f);
        if (c == t4) {  // rare: exactly one chunk per row
            const int k = t & 3;
            if      (k == 0) { v.x = ctm_t; o0.x = 1.f; }
            else if (k == 1) { v.y = ctm_t; o0.y = 1.f; }
            else if (k == 2) { v.z = ctm_t; o1.x = 1.f; }
            else             { v.w = ctm_t; o1.y = 1.f; }
        }
        oh2[2 * c]     = o0;
        oh2[2 * c + 1] = o1;

        const float cmax = fmaxf(fmaxf(v.x, v.y), fmaxf(v.z, v.w));
        const float mn   = fmaxf(m, cmax);
        s = s * __expf(m - mn)
          + __expf(v.x - mn) + __expf(v.y - mn)
          + __expf(v.z - mn) + __expf(v.w - mn);
        m = mn;
    }

    // scalar tail (C % 4 != 0) — no-op for C=100000
    for (int j = (nchunk << 2) + (int)threadIdx.x; j < C; j += blockDim.x) {
        const bool is_t = (j == t);
        const float v = is_t ? ctm_t : ct[base + (size_t)j];
        onehot[base + (size_t)j] = is_t ? 1.f : 0.f;
        const float mn = fmaxf(m, v);
        s = s * __expf(m - mn) + __expf(v - mn);
        m = mn;
    }

    // wave (64-lane) reduce of (m, s)
    #pragma unroll
    for (int off = 32; off; off >>= 1) {
        const float mo = __shfl_xor(m, off);
        const float so = __shfl_xor(s, off);
        const float M  = fmaxf(m, mo);
        s = s * __expf(m - M) + so * __expf(mo - M);
        m = M;
    }

    __shared__ float sm[16], ss[16];
    const int wave = threadIdx.x >> 6;
    const int lane = threadIdx.x & 63;
    if (lane == 0) { sm[wave] = m; ss[wave] = s; }
    __syncthreads();

    if (threadIdx.x == 0) {
        const int nwaves = blockDim.x >> 6;
        float M = sm[0], S = ss[0];
        for (int w = 1; w < nwaves; ++w) {
            const float mo = sm[w], so = ss[w];
            const float Mn = fmaxf(M, mo);
            S = S * __expf(M - Mn) + so * __expf(mo - Mn);
            M = Mn;
        }
        // loss_i = LSE_i - output[i, t] = (M + log S) - ctm_t
        row_loss[row] = M + __logf(S) - ctm_t;
    }
}

__global__ __launch_bounds__(256) void magloss_finalize_kernel(
    const float* __restrict__ row_loss, // ws [B]
    const float* __restrict__ x_norm,   // [B]
    float*       __restrict__ out,      // d_out (out[0], out[1])
    int B)
{
    const int i = threadIdx.x;
    float l = 0.f, g = 0.f;
    for (int j = i; j < B; j += blockDim.x) {
        l += row_loss[j];
        const float xn = x_norm[j];
        g += xn * UA2_INV + 1.0f / xn;
    }
    #pragma unroll
    for (int off = 32; off; off >>= 1) {
        l += __shfl_xor(l, off);
        g += __shfl_xor(g, off);
    }
    __shared__ float sl[4], sg[4];
    const int wave = i >> 6;
    const int lane = i & 63;
    if (lane == 0) { sl[wave] = l; sg[wave] = g; }
    __syncthreads();
    if (i == 0) {
        const int nw = blockDim.x >> 6;
        float L = 0.f, G = 0.f;
        for (int w = 0; w < nw; ++w) { L += sl[w]; G += sg[w]; }
        out[0] = L / (float)B;
        out[1] = G / (float)B;
    }
}

extern "C" void kernel_launch(void* const* d_in, const int* in_sizes, int n_in,
                              void* d_out, int out_size, void* d_ws, size_t ws_size,
                              hipStream_t stream) {
    const float* ct  = (const float*)d_in[0];
    const float* ctm = (const float*)d_in[1];
    const float* xn  = (const float*)d_in[2];
    const int*   tg  = (const int*)d_in[3];

    const int B = in_sizes[2];
    const int C = in_sizes[0] / B;

    float* out      = (float*)d_out;
    float* row_loss = (float*)d_ws;

    magloss_row_kernel<<<B, 1024, 0, stream>>>(ct, ctm, tg, out + 2, row_loss, C);
    magloss_finalize_kernel<<<1, 256, 0, stream>>>(row_loss, xn, out, B);
}